// Round 11
// baseline (219.377 us; speedup 1.0000x reference)
//
#include <hip/hip_runtime.h>
#include <math.h>

#define NB 4
#define CIN 64
#define DM 32
#define S 4096
#define NW 4

// ws float-offsets (~7.7 MB; under the 8 MB proven in round 2)
#define OFF_Q  0          // bf16 [n][s][32]  (scaled by log2e/sqrt(32))
#define OFF_KH 262144     // bf16 [n][s][32]
#define OFF_VH 524288     // bf16 [n][c][s]
#define OFF_KM 786432     // bf16 [n][s][32]
#define OFF_VM 1048576    // bf16 [n][c][s]
#define OFF_ZH 1310720    // bf16 [n][32][s]
#define OFF_ZM 1572864    // bf16 [n][32][s]
#define OFF_WF 1835008    // bf16 [192 co][864 k]  (k = tap*96 + ci), 324 KB

typedef __attribute__((ext_vector_type(8))) short bf16x8;
typedef __attribute__((ext_vector_type(4))) short s16x4;
typedef __attribute__((ext_vector_type(4))) float f32x4;
typedef __attribute__((ext_vector_type(2))) unsigned int u32x2;

__device__ inline unsigned short f2b(float x) {
  union { float f; unsigned u; } v;
  v.f = x;
  unsigned r = (v.u + 0x7FFF + ((v.u >> 16) & 1)) >> 16;
  return (unsigned short)r;
}

__device__ inline float b2f(unsigned short u) {
  union { unsigned u; float f; } v;
  v.u = ((unsigned)u) << 16;
  return v.f;
}

__device__ inline unsigned fbits(float x) {
  union { float f; unsigned u; } v;
  v.f = x;
  return v.u;
}

// ---------------- K1: fused prep: proj(h), proj(m), wprep ----------------
__global__ __launch_bounds__(256) void prep_kernel(
    const float* __restrict__ h, const float* __restrict__ m,
    const float* __restrict__ Wh, const float* __restrict__ bh,
    const float* __restrict__ Wm, const float* __restrict__ bm,
    const float* __restrict__ Wo, float* __restrict__ ws) {
  __shared__ unsigned short sm[64][34];
  int bid = blockIdx.x;
  int tid = threadIdx.x;

  if (bid >= 512) {  // ---- wprep
    int idx = (bid - 512) * 256 + tid;  // 82944 uints
    int co = idx / 432;
    int rem = idx - co * 432;
    int tap = rem / 48;
    int cp = rem - tap * 48;
    int ci0 = cp * 2;
    float a = Wo[((size_t)co * 96 + ci0) * 9 + tap];
    float b = Wo[((size_t)co * 96 + ci0 + 1) * 9 + tap];
    unsigned val = (unsigned)f2b(a) | ((unsigned)f2b(b) << 16);
    ((unsigned*)(ws + OFF_WF))[idx] = val;
    return;
  }

  int mode = (bid >= 256) ? 1 : 0;
  const float* in = mode ? m : h;
  const float* W = mode ? Wm : Wh;
  const float* b = mode ? bm : bh;
  int lbid = bid & 255;
  int n = lbid >> 6;
  int s0 = (lbid & 63) * 64;
  int sl = tid & 63;
  int cg = tid >> 6;
  const float* inp = in + (size_t)n * CIN * S + s0 + sl;

  float reg[64];
#pragma unroll
  for (int ci = 0; ci < 64; ++ci) reg[ci] = inp[(size_t)ci * S];

  float acc[24];
  if (mode == 0) {
#pragma unroll
    for (int k = 0; k < 24; ++k) {
      int co = cg + k * 4;
      const float* w = W + co * CIN;
      float a = b[co];
#pragma unroll
      for (int ci = 0; ci < CIN; ++ci) a += w[ci] * reg[ci];
      acc[k] = a;
    }
  } else {
#pragma unroll
    for (int k = 0; k < 16; ++k) {
      int co = cg + k * 4;
      const float* w = W + co * CIN;
      float a = b[co];
#pragma unroll
      for (int ci = 0; ci < CIN; ++ci) a += w[ci] * reg[ci];
      acc[k] = a;
    }
  }

  unsigned short* qsl = (unsigned short*)(ws + OFF_Q);
  unsigned short* khs = (unsigned short*)(ws + OFF_KH);
  unsigned short* vhs = (unsigned short*)(ws + OFF_VH);
  unsigned short* kms = (unsigned short*)(ws + OFF_KM);
  unsigned short* vms = (unsigned short*)(ws + OFF_VM);

  int ngrp = (mode == 0) ? 2 : 1;
  for (int g = 0; g < ngrp; ++g) {
    __syncthreads();
    const float rs = 0.2550400330665387f;  // log2e / sqrt(32)
#pragma unroll
    for (int j = 0; j < 8; ++j) {
      int k = g * 8 + j;
      int c = cg + 4 * j;
      float v = acc[k];
      if (mode == 0 && g == 0) v *= rs;
      sm[sl][c] = f2b(v);
    }
    __syncthreads();
    unsigned short* dst;
    if (mode == 0)
      dst = (g == 0 ? qsl : khs);
    else
      dst = kms;
    unsigned* du = (unsigned*)(dst + ((size_t)n * S + s0) * 32);
#pragma unroll
    for (int i = 0; i < 4; ++i) {
      int idx = tid + i * 256;
      int s = idx >> 4, cp = idx & 15;
      unsigned val = (unsigned)sm[s][2 * cp] | ((unsigned)sm[s][2 * cp + 1] << 16);
      du[idx] = val;
    }
  }
  int k0 = (mode == 0) ? 16 : 8;
  unsigned short* vdst = (mode == 0) ? vhs : vms;
#pragma unroll
  for (int j = 0; j < 8; ++j) {
    int k = k0 + j;
    int c = cg + 4 * j;
    vdst[((size_t)n * DM + c) * S + s0 + sl] = f2b(acc[k]);
  }
}

// ---------------- K2: MFMA flash attention, K-split x4, P ping-pong -------
// Iteration it: QK/exp/write tile it into buf it&1, PV of tile it-1 from
// buf (it-1)&1.  The P reads are issued EARLY (right after a lgkm drain of
// ~1-iteration-old writes) and their latency hides under the QK/exp VALU
// work; the write->read LDS round-trip leaves the critical path.
union AttnSmem {
  unsigned short P[NW][2][2][1024];  // [wave][buf][qtile][16 rows x 64 keys]
  float osh[NW][2][32][16];          // merge partials — epilogue overlay
};

__global__ __launch_bounds__(256, 4) void attn_kernel(
    float* __restrict__ ws, const float* __restrict__ Wz,
    const float* __restrict__ bz) {
  __shared__ __align__(16) AttnSmem sm;
  __shared__ float lsh[NW][2][16];
  __shared__ unsigned short Olds[2][16][40];

  int bid = blockIdx.x;
  int ph = bid & 1;
  int n = (bid >> 1) & 3;
  int q0 = (bid >> 3) * 32;
  int tid = threadIdx.x;
  int w = tid >> 6;
  int lane = tid & 63;
  int ql = lane & 15;
  int quad = lane >> 4;
  int kbase = w * 1024;
  int sw = 2 * (ql & 7);  // granule XOR swizzle (even -> 16B reads stay aligned)

  const unsigned short* qs = (const unsigned short*)(ws + OFF_Q) + ((size_t)n * S + q0) * 32;
  const unsigned short* Ks = (const unsigned short*)(ws + (ph ? OFF_KM : OFF_KH)) + (size_t)n * S * 32;
  const unsigned short* Vs = (const unsigned short*)(ws + (ph ? OFF_VM : OFF_VH)) + (size_t)n * DM * S;
  unsigned short* Zp = (unsigned short*)(ws + (ph ? OFF_ZM : OFF_ZH)) + (size_t)n * DM * S;

  bf16x8 qf0 = *(const bf16x8*)(qs + ql * 32 + quad * 8);
  bf16x8 qf1 = *(const bf16x8*)(qs + (16 + ql) * 32 + quad * 8);

  f32x4 o00 = {0.f, 0.f, 0.f, 0.f}, o01 = {0.f, 0.f, 0.f, 0.f};
  f32x4 o10 = {0.f, 0.f, 0.f, 0.f}, o11 = {0.f, 0.f, 0.f, 0.f};
  f32x4 lsv0 = {0.f, 0.f, 0.f, 0.f}, lsv1 = {0.f, 0.f, 0.f, 0.f};
  const float ZI = -11.541560327111707f;  // -8 * log2(e)
  const f32x4 zinit = {ZI, ZI, ZI, ZI};

  // QK + exp + pack + inline write of tile (kf) into buf pb
  auto qkexp = [&](bf16x8(&kfc)[4], int pb) {
#pragma unroll
    for (int t = 0; t < 4; ++t) {
      f32x4 stt = __builtin_amdgcn_mfma_f32_16x16x32_bf16(kfc[t], qf0, zinit, 0, 0, 0);
      f32x4 e;
#pragma unroll
      for (int r = 0; r < 4; ++r) e[r] = __builtin_amdgcn_exp2f(stt[r]);
      lsv0 += e;
      u32x2 pk;
      pk[0] = __builtin_amdgcn_perm(fbits(e[1]), fbits(e[0]), 0x07060302u);
      pk[1] = __builtin_amdgcn_perm(fbits(e[3]), fbits(e[2]), 0x07060302u);
      *(u32x2*)(&sm.P[w][pb][0][ql * 64 + ((t * 4 + quad) ^ sw) * 4]) = pk;
    }
#pragma unroll
    for (int t = 0; t < 4; ++t) {
      f32x4 stt = __builtin_amdgcn_mfma_f32_16x16x32_bf16(kfc[t], qf1, zinit, 0, 0, 0);
      f32x4 e;
#pragma unroll
      for (int r = 0; r < 4; ++r) e[r] = __builtin_amdgcn_exp2f(stt[r]);
      lsv1 += e;
      u32x2 pk;
      pk[0] = __builtin_amdgcn_perm(fbits(e[1]), fbits(e[0]), 0x07060302u);
      pk[1] = __builtin_amdgcn_perm(fbits(e[3]), fbits(e[2]), 0x07060302u);
      *(u32x2*)(&sm.P[w][pb][1][ql * 64 + ((t * 4 + quad) ^ sw) * 4]) = pk;
    }
  };

  bf16x8 kfa[4], kfb[4], vfa[4], vfb[4];
  // ---- prologue: K0/V0/K1 loads; tile 0 scores into buf 0 ----
#pragma unroll
  for (int t = 0; t < 4; ++t)
    kfa[t] = *(const bf16x8*)(Ks + (size_t)(kbase + t * 16 + ql) * 32 + quad * 8);
#pragma unroll
  for (int c2 = 0; c2 < 2; ++c2)
#pragma unroll
    for (int t2 = 0; t2 < 2; ++t2)
      vfa[c2 * 2 + t2] = *(const bf16x8*)(Vs + (size_t)(t2 * 16 + ql) * S + kbase + c2 * 32 + quad * 8);
#pragma unroll
  for (int t = 0; t < 4; ++t)
    kfb[t] = *(const bf16x8*)(Ks + (size_t)(kbase + 64 + t * 16 + ql) * 32 + quad * 8);
  qkexp(kfa, 0);

  // ---- steady state: QK(it) + PV(it-1) ----
  auto step = [&](int it, bf16x8(&kfc)[4], bf16x8(&kfn)[4],
                  bf16x8(&vfp)[4], bf16x8(&vfc)[4]) {
    int kbc = kbase + it * 64;
    int kbn = kbase + ((it + 1) & 15) * 64;
    int pbc = it & 1, pbp = pbc ^ 1;
#pragma unroll
    for (int t = 0; t < 4; ++t)
      kfn[t] = *(const bf16x8*)(Ks + (size_t)(kbn + t * 16 + ql) * 32 + quad * 8);
#pragma unroll
    for (int c2 = 0; c2 < 2; ++c2)
#pragma unroll
      for (int t2 = 0; t2 < 2; ++t2)
        vfc[c2 * 2 + t2] = *(const bf16x8*)(Vs + (size_t)(t2 * 16 + ql) * S + kbc + c2 * 32 + quad * 8);
    // drain prev-buf writes (issued ~1 iteration ago), then read prev P EARLY
    __builtin_amdgcn_s_waitcnt(0xC07F);
    __builtin_amdgcn_wave_barrier();
    bf16x8 pf[4];
#pragma unroll
    for (int c2 = 0; c2 < 2; ++c2) {
      pf[c2] = *(const bf16x8*)(&sm.P[w][pbp][0][ql * 64 + ((c2 * 8 + quad * 2) ^ sw) * 4]);
      pf[2 + c2] = *(const bf16x8*)(&sm.P[w][pbp][1][ql * 64 + ((c2 * 8 + quad * 2) ^ sw) * 4]);
    }
    // current tile scores (hides the pf read latency)
    qkexp(kfc, pbc);
    // PV of previous tile
#pragma unroll
    for (int c2 = 0; c2 < 2; ++c2) {
      o00 = __builtin_amdgcn_mfma_f32_16x16x32_bf16(vfp[c2 * 2 + 0], pf[c2], o00, 0, 0, 0);
      o01 = __builtin_amdgcn_mfma_f32_16x16x32_bf16(vfp[c2 * 2 + 1], pf[c2], o01, 0, 0, 0);
      o10 = __builtin_amdgcn_mfma_f32_16x16x32_bf16(vfp[c2 * 2 + 0], pf[2 + c2], o10, 0, 0, 0);
      o11 = __builtin_amdgcn_mfma_f32_16x16x32_bf16(vfp[c2 * 2 + 1], pf[2 + c2], o11, 0, 0, 0);
    }
  };

  step(1, kfb, kfa, vfa, vfb);
#pragma unroll 1
  for (int it = 2; it < 16; it += 2) {
    step(it, kfa, kfb, vfb, vfa);
    step(it + 1, kfb, kfa, vfa, vfb);
  }

  // ---- epilogue: PV of tile 15 (buf 1, V in vfb) ----
  __builtin_amdgcn_s_waitcnt(0xC07F);
  __builtin_amdgcn_wave_barrier();
#pragma unroll
  for (int c2 = 0; c2 < 2; ++c2) {
    bf16x8 pf0 = *(const bf16x8*)(&sm.P[w][1][0][ql * 64 + ((c2 * 8 + quad * 2) ^ sw) * 4]);
    bf16x8 pf1 = *(const bf16x8*)(&sm.P[w][1][1][ql * 64 + ((c2 * 8 + quad * 2) ^ sw) * 4]);
    o00 = __builtin_amdgcn_mfma_f32_16x16x32_bf16(vfb[c2 * 2 + 0], pf0, o00, 0, 0, 0);
    o01 = __builtin_amdgcn_mfma_f32_16x16x32_bf16(vfb[c2 * 2 + 1], pf0, o01, 0, 0, 0);
    o10 = __builtin_amdgcn_mfma_f32_16x16x32_bf16(vfb[c2 * 2 + 0], pf1, o10, 0, 0, 0);
    o11 = __builtin_amdgcn_mfma_f32_16x16x32_bf16(vfb[c2 * 2 + 1], pf1, o11, 0, 0, 0);
  }

  float lrun0 = lsv0[0] + lsv0[1] + lsv0[2] + lsv0[3];
  float lrun1 = lsv1[0] + lsv1[1] + lsv1[2] + lsv1[3];
  lrun0 += __shfl_xor(lrun0, 16);
  lrun0 += __shfl_xor(lrun0, 32);
  lrun1 += __shfl_xor(lrun1, 16);
  lrun1 += __shfl_xor(lrun1, 32);

  __syncthreads();  // all waves done with P before epilogue overlay
#pragma unroll
  for (int r = 0; r < 4; ++r) {
    sm.osh[w][0][quad * 4 + r][ql] = o00[r];
    sm.osh[w][0][16 + quad * 4 + r][ql] = o01[r];
    sm.osh[w][1][quad * 4 + r][ql] = o10[r];
    sm.osh[w][1][16 + quad * 4 + r][ql] = o11[r];
  }
  if (quad == 0) {
    lsh[w][0][ql] = lrun0;
    lsh[w][1][ql] = lrun1;
  }
  __syncthreads();

  if (w < 2) {
    int qt = w;
    float l = 0.f;
    f32x4 a0 = {0.f, 0.f, 0.f, 0.f}, a1 = {0.f, 0.f, 0.f, 0.f};
#pragma unroll
    for (int i = 0; i < NW; ++i) {
      l += lsh[i][qt][ql];
#pragma unroll
      for (int r = 0; r < 4; ++r) {
        a0[r] += sm.osh[i][qt][quad * 4 + r][ql];
        a1[r] += sm.osh[i][qt][16 + quad * 4 + r][ql];
      }
    }
    float inv = 1.0f / l;
    s16x4 w0, w1;
#pragma unroll
    for (int r = 0; r < 4; ++r) {
      w0[r] = (short)f2b(a0[r] * inv);
      w1[r] = (short)f2b(a1[r] * inv);
    }
    *(s16x4*)(&Olds[qt][ql][quad * 4]) = w0;
    *(s16x4*)(&Olds[qt][ql][16 + quad * 4]) = w1;
    __builtin_amdgcn_s_waitcnt(0xC07F);
    __builtin_amdgcn_wave_barrier();
    bf16x8 of = *(const bf16x8*)(&Olds[qt][ql][quad * 8]);

    const float* wzr0 = Wz + (size_t)ql * (2 * DM) + ph * DM + quad * 8;
    const float* wzr1 = Wz + (size_t)(ql + 16) * (2 * DM) + ph * DM + quad * 8;
    bf16x8 a0f, a1f;
#pragma unroll
    for (int j = 0; j < 8; ++j) {
      a0f[j] = (short)f2b(wzr0[j]);
      a1f[j] = (short)f2b(wzr1[j]);
    }
    f32x4 z0 = {0.f, 0.f, 0.f, 0.f}, z1 = {0.f, 0.f, 0.f, 0.f};
    if (ph == 0) {
#pragma unroll
      for (int r = 0; r < 4; ++r) {
        z0[r] = bz[quad * 4 + r];
        z1[r] = bz[16 + quad * 4 + r];
      }
    }
    z0 = __builtin_amdgcn_mfma_f32_16x16x32_bf16(a0f, of, z0, 0, 0, 0);
    z1 = __builtin_amdgcn_mfma_f32_16x16x32_bf16(a1f, of, z1, 0, 0, 0);
    int qc = q0 + qt * 16 + ql;
#pragma unroll
    for (int r = 0; r < 4; ++r) {
      Zp[(size_t)(quad * 4 + r) * S + qc] = f2b(z0[r]);
      Zp[(size_t)(16 + quad * 4 + r) * S + qc] = f2b(z1[r]);
    }
  }
}

// ---------------- K3: fused xs-halo + implicit-GEMM MFMA conv + gating ----
__global__ __launch_bounds__(256) void conv_mfma_kernel(
    const float* __restrict__ ws, const float* __restrict__ h,
    const float* __restrict__ m, const float* __restrict__ bo,
    float* __restrict__ out) {
  __shared__ unsigned short xt[3][66][104];  // 41184 B
  int bid = blockIdx.x;
  int n = bid >> 7;
  int rem = bid & 127;
  int g = rem & 1;
  int y = rem >> 1;
  int tid = threadIdx.x;
  int wv = tid >> 6;
  int lane = tid & 63;
  int ql = lane & 15, quad = lane >> 4;
  int x0 = wv * 16;

  const unsigned short* Zh = (const unsigned short*)(ws + OFF_ZH) + (size_t)n * DM * S;
  const unsigned short* Zm = (const unsigned short*)(ws + OFF_ZM) + (size_t)n * DM * S;
  const float* hb = h + (size_t)n * CIN * S;
  const unsigned short* Wf = (const unsigned short*)(ws + OFF_WF);

#pragma unroll
  for (int k = 0; k < 36; ++k) {
    int idx = tid + k * 256;
    int xm1 = idx & 63;
    int t2 = idx >> 6;
    int cp = t2 % 48;
    int r3 = t2 / 48;
    int yy = y + r3 - 1;
    unsigned val = 0u;
    if (yy >= 0 && yy < 64) {
      int s = yy * 64 + xm1;
      int ci0 = 2 * cp;
      float a, b;
      if (ci0 < 32) {
        a = b2f(Zh[(size_t)ci0 * S + s]) + b2f(Zm[(size_t)ci0 * S + s]);
        b = b2f(Zh[(size_t)(ci0 + 1) * S + s]) + b2f(Zm[(size_t)(ci0 + 1) * S + s]);
      } else {
        a = hb[(size_t)(ci0 - 32) * S + s];
        b = hb[(size_t)(ci0 - 31) * S + s];
      }
      val = (unsigned)f2b(a) | ((unsigned)f2b(b) << 16);
    }
    *(unsigned*)(&xt[r3][xm1 + 1][2 * cp]) = val;
  }
#pragma unroll
  for (int k = 0; k < 2; ++k) {
    int idx = tid + k * 256;
    if (idx < 288) {
      int r3 = idx / 96;
      int rm = idx % 96;
      int side = rm / 48;
      int cp = rm % 48;
      *(unsigned*)(&xt[r3][side * 65][2 * cp]) = 0u;
    }
  }
  __syncthreads();

  f32x4 acc[6];
#pragma unroll
  for (int t = 0; t < 6; ++t) acc[t] = (f32x4){0.f, 0.f, 0.f, 0.f};

  const unsigned short* wb[6];
#pragma unroll
  for (int j = 0; j < 6; ++j) {
    int cob = (j >> 1) * 64 + g * 32 + (j & 1) * 16;
    wb[j] = Wf + (size_t)(cob + ql) * 864 + quad * 8;
  }

#pragma unroll
  for (int dy = 0; dy < 3; ++dy) {
#pragma unroll
    for (int dx = 0; dx < 3; ++dx) {
      int tap = dy * 3 + dx;
#pragma unroll
      for (int cc = 0; cc < 3; ++cc) {
        bf16x8 b = *(const bf16x8*)(&xt[dy][x0 + ql + dx][cc * 32 + quad * 8]);
        int ko = tap * 96 + cc * 32;
#pragma unroll
        for (int j = 0; j < 6; ++j) {
          bf16x8 wf = *(const bf16x8*)(wb[j] + ko);
          acc[j] = __builtin_amdgcn_mfma_f32_16x16x32_bf16(wf, b, acc[j], 0, 0, 0);
        }
      }
    }
  }

  int s = y * 64 + x0 + ql;
#pragma unroll
  for (int jj = 0; jj < 2; ++jj) {
#pragma unroll
    for (int r = 0; r < 4; ++r) {
      int c = g * 32 + jj * 16 + quad * 4 + r;
      float iv = acc[jj][r] + bo[c];
      float gv = acc[2 + jj][r] + bo[64 + c];
      float ov = acc[4 + jj][r] + bo[128 + c];
      float ig = 1.f / (1.f + __expf(-iv));
      float gg = tanhf(gv);
      float og = 1.f / (1.f + __expf(-ov));
      size_t oidx = (((size_t)n * 64 + c) << 12) + s;
      float mold = m[oidx];
      float mn = ig * gg + (1.f - ig) * mold;
      out[oidx] = og * mn;
      out[(size_t)NB * CIN * S + oidx] = mn;
    }
  }
}

extern "C" void kernel_launch(void* const* d_in, const int* in_sizes, int n_in,
                              void* d_out, int out_size, void* d_ws, size_t ws_size,
                              hipStream_t stream) {
  const float* h = (const float*)d_in[0];
  const float* m = (const float*)d_in[1];
  const float* Wh = (const float*)d_in[2];
  const float* bh = (const float*)d_in[3];
  const float* Wm = (const float*)d_in[4];
  const float* bm = (const float*)d_in[5];
  const float* Wz = (const float*)d_in[6];
  const float* bz = (const float*)d_in[7];
  const float* Wo = (const float*)d_in[8];
  const float* bo = (const float*)d_in[9];
  float* out = (float*)d_out;
  float* ws = (float*)d_ws;

  prep_kernel<<<836, 256, 0, stream>>>(h, m, Wh, bh, Wm, bm, Wo, ws);
  attn_kernel<<<2 * NB * (S / 32), 256, 0, stream>>>(ws, Wz, bz);
  conv_mfma_kernel<<<NB * 128, 256, 0, stream>>>(ws, h, m, bo, out);
}

// Round 12
// 185.008 us; speedup vs baseline: 1.1858x; 1.1858x over previous
//
#include <hip/hip_runtime.h>
#include <math.h>

#define NB 4
#define CIN 64
#define DM 32
#define S 4096
#define NW 4

// ws float-offsets (~7.7 MB; under the 8 MB proven in round 2)
#define OFF_Q  0          // bf16 [n][s][32]  (scaled by log2e/sqrt(32))
#define OFF_KH 262144     // bf16 [n][s][32]
#define OFF_VH 524288     // bf16 [n][c][s]
#define OFF_KM 786432     // bf16 [n][s][32]
#define OFF_VM 1048576    // bf16 [n][c][s]
#define OFF_ZH 1310720    // bf16 [n][32][s]
#define OFF_ZM 1572864    // bf16 [n][32][s]
#define OFF_WF 1835008    // bf16 Wf2[324 frags][64 lanes][8]  (A-frag order)

typedef __attribute__((ext_vector_type(8))) short bf16x8;
typedef __attribute__((ext_vector_type(4))) short s16x4;
typedef __attribute__((ext_vector_type(4))) float f32x4;
typedef __attribute__((ext_vector_type(2))) unsigned int u32x2;

__device__ inline unsigned short f2b(float x) {
  union { float f; unsigned u; } v;
  v.f = x;
  unsigned r = (v.u + 0x7FFF + ((v.u >> 16) & 1)) >> 16;
  return (unsigned short)r;
}

__device__ inline float b2f(unsigned short u) {
  union { unsigned u; float f; } v;
  v.u = ((unsigned)u) << 16;
  return v.f;
}

__device__ inline unsigned fbits(float x) {
  union { float f; unsigned u; } v;
  v.f = x;
  return v.u;
}

// ---------------- K1: fused prep: proj(h), proj(m), wprep ----------------
// wprep emits Wf2 in MFMA A-fragment order: frag f = t12*27 + kb covers
// rows t12*16..+15, k = kb*32..+31 (k = tap*96+ci); element (lane, j) =
// A[row = 16*t12 + (lane&15)][k = kb*32 + (lane>>4)*8 + j].  A wave's
// 16-B/lane load of one frag is then a single contiguous 1-KB burst.
__global__ __launch_bounds__(256) void prep_kernel(
    const float* __restrict__ h, const float* __restrict__ m,
    const float* __restrict__ Wh, const float* __restrict__ bh,
    const float* __restrict__ Wm, const float* __restrict__ bm,
    const float* __restrict__ Wo, float* __restrict__ ws) {
  __shared__ unsigned short sm[64][34];
  int bid = blockIdx.x;
  int tid = threadIdx.x;

  if (bid >= 512) {  // ---- wprep: 82944 uints
    int idx = (bid - 512) * 256 + tid;
    int f = idx >> 8;          // 256 uints per frag
    int r = idx & 255;
    int lane = r >> 2;         // 4 uints per lane
    int jp = (r & 3) * 2;      // even j
    int ql = lane & 15, quad = lane >> 4;
    int co = (f / 27) * 16 + ql;
    int k = (f % 27) * 32 + quad * 8 + jp;
    int tap = k / 96;
    int ci = k - tap * 96;     // even; ci+1 never crosses the tap boundary
    float a = Wo[((size_t)co * 96 + ci) * 9 + tap];
    float b = Wo[((size_t)co * 96 + ci + 1) * 9 + tap];
    unsigned val = (unsigned)f2b(a) | ((unsigned)f2b(b) << 16);
    ((unsigned*)(ws + OFF_WF))[idx] = val;
    return;
  }

  int mode = (bid >= 256) ? 1 : 0;
  const float* in = mode ? m : h;
  const float* W = mode ? Wm : Wh;
  const float* b = mode ? bm : bh;
  int lbid = bid & 255;
  int n = lbid >> 6;
  int s0 = (lbid & 63) * 64;
  int sl = tid & 63;
  int cg = tid >> 6;
  const float* inp = in + (size_t)n * CIN * S + s0 + sl;

  float reg[64];
#pragma unroll
  for (int ci = 0; ci < 64; ++ci) reg[ci] = inp[(size_t)ci * S];

  float acc[24];
  if (mode == 0) {
#pragma unroll
    for (int k = 0; k < 24; ++k) {
      int co = cg + k * 4;
      const float* w = W + co * CIN;
      float a = b[co];
#pragma unroll
      for (int ci = 0; ci < CIN; ++ci) a += w[ci] * reg[ci];
      acc[k] = a;
    }
  } else {
#pragma unroll
    for (int k = 0; k < 16; ++k) {
      int co = cg + k * 4;
      const float* w = W + co * CIN;
      float a = b[co];
#pragma unroll
      for (int ci = 0; ci < CIN; ++ci) a += w[ci] * reg[ci];
      acc[k] = a;
    }
  }

  unsigned short* qsl = (unsigned short*)(ws + OFF_Q);
  unsigned short* khs = (unsigned short*)(ws + OFF_KH);
  unsigned short* vhs = (unsigned short*)(ws + OFF_VH);
  unsigned short* kms = (unsigned short*)(ws + OFF_KM);
  unsigned short* vms = (unsigned short*)(ws + OFF_VM);

  int ngrp = (mode == 0) ? 2 : 1;
  for (int g = 0; g < ngrp; ++g) {
    __syncthreads();
    const float rs = 0.2550400330665387f;  // log2e / sqrt(32)
#pragma unroll
    for (int j = 0; j < 8; ++j) {
      int k = g * 8 + j;
      int c = cg + 4 * j;
      float v = acc[k];
      if (mode == 0 && g == 0) v *= rs;
      sm[sl][c] = f2b(v);
    }
    __syncthreads();
    unsigned short* dst;
    if (mode == 0)
      dst = (g == 0 ? qsl : khs);
    else
      dst = kms;
    unsigned* du = (unsigned*)(dst + ((size_t)n * S + s0) * 32);
#pragma unroll
    for (int i = 0; i < 4; ++i) {
      int idx = tid + i * 256;
      int s = idx >> 4, cp = idx & 15;
      unsigned val = (unsigned)sm[s][2 * cp] | ((unsigned)sm[s][2 * cp + 1] << 16);
      du[idx] = val;
    }
  }
  int k0 = (mode == 0) ? 16 : 8;
  unsigned short* vdst = (mode == 0) ? vhs : vms;
#pragma unroll
  for (int j = 0; j < 8; ++j) {
    int k = k0 + j;
    int c = cg + 4 * j;
    vdst[((size_t)n * DM + c) * S + s0 + sl] = f2b(acc[k]);
  }
}

// ---------------- K2: MFMA flash attention, K-split x4 (round-10 exact) ---
union AttnSmem {
  unsigned short P[NW][2][1024];   // [wave][qtile][16 rows x 64 keys]
  float osh[NW][2][32][16];        // merge partials — epilogue overlay
};

__global__ __launch_bounds__(256, 4) void attn_kernel(
    float* __restrict__ ws, const float* __restrict__ Wz,
    const float* __restrict__ bz) {
  __shared__ __align__(16) AttnSmem sm;
  __shared__ float lsh[NW][2][16];
  __shared__ unsigned short Olds[2][16][40];

  int bid = blockIdx.x;
  int ph = bid & 1;
  int n = (bid >> 1) & 3;
  int q0 = (bid >> 3) * 32;
  int tid = threadIdx.x;
  int w = tid >> 6;
  int lane = tid & 63;
  int ql = lane & 15;
  int quad = lane >> 4;
  int kbase = w * 1024;
  int sw = 2 * (ql & 7);           // granule XOR swizzle (even)

  const unsigned short* qs = (const unsigned short*)(ws + OFF_Q) + ((size_t)n * S + q0) * 32;
  const unsigned short* Ks = (const unsigned short*)(ws + (ph ? OFF_KM : OFF_KH)) + (size_t)n * S * 32;
  const unsigned short* Vs = (const unsigned short*)(ws + (ph ? OFF_VM : OFF_VH)) + (size_t)n * DM * S;
  unsigned short* Zp = (unsigned short*)(ws + (ph ? OFF_ZM : OFF_ZH)) + (size_t)n * DM * S;

  bf16x8 qf0 = *(const bf16x8*)(qs + ql * 32 + quad * 8);
  bf16x8 qf1 = *(const bf16x8*)(qs + (16 + ql) * 32 + quad * 8);

  f32x4 o00 = {0.f, 0.f, 0.f, 0.f}, o01 = {0.f, 0.f, 0.f, 0.f};
  f32x4 o10 = {0.f, 0.f, 0.f, 0.f}, o11 = {0.f, 0.f, 0.f, 0.f};
  f32x4 lsv0 = {0.f, 0.f, 0.f, 0.f}, lsv1 = {0.f, 0.f, 0.f, 0.f};
  const float ZI = -11.541560327111707f;  // -8 * log2(e)
  const f32x4 zinit = {ZI, ZI, ZI, ZI};

  bf16x8 kfa[4], kfb[4];
#pragma unroll
  for (int t = 0; t < 4; ++t)
    kfa[t] = *(const bf16x8*)(Ks + (size_t)(kbase + t * 16 + ql) * 32 + quad * 8);

  auto step = [&](bf16x8 (&kfc)[4], bf16x8 (&kfn)[4], int kb, int kbn) {
    bf16x8 vf[4];
#pragma unroll
    for (int c2 = 0; c2 < 2; ++c2)
#pragma unroll
      for (int t2 = 0; t2 < 2; ++t2)
        vf[c2 * 2 + t2] = *(const bf16x8*)(Vs + (size_t)(t2 * 16 + ql) * S + kb + c2 * 32 + quad * 8);
#pragma unroll
    for (int t = 0; t < 4; ++t)
      kfn[t] = *(const bf16x8*)(Ks + (size_t)(kbn + t * 16 + ql) * 32 + quad * 8);

#pragma unroll
    for (int t = 0; t < 4; ++t) {
      f32x4 stt = __builtin_amdgcn_mfma_f32_16x16x32_bf16(kfc[t], qf0, zinit, 0, 0, 0);
      f32x4 e;
#pragma unroll
      for (int r = 0; r < 4; ++r) e[r] = __builtin_amdgcn_exp2f(stt[r]);
      lsv0 += e;
      u32x2 pk;
      pk[0] = __builtin_amdgcn_perm(fbits(e[1]), fbits(e[0]), 0x07060302u);
      pk[1] = __builtin_amdgcn_perm(fbits(e[3]), fbits(e[2]), 0x07060302u);
      *(u32x2*)(&sm.P[w][0][ql * 64 + ((t * 4 + quad) ^ sw) * 4]) = pk;
    }
#pragma unroll
    for (int t = 0; t < 4; ++t) {
      f32x4 stt = __builtin_amdgcn_mfma_f32_16x16x32_bf16(kfc[t], qf1, zinit, 0, 0, 0);
      f32x4 e;
#pragma unroll
      for (int r = 0; r < 4; ++r) e[r] = __builtin_amdgcn_exp2f(stt[r]);
      lsv1 += e;
      u32x2 pk;
      pk[0] = __builtin_amdgcn_perm(fbits(e[1]), fbits(e[0]), 0x07060302u);
      pk[1] = __builtin_amdgcn_perm(fbits(e[3]), fbits(e[2]), 0x07060302u);
      *(u32x2*)(&sm.P[w][1][ql * 64 + ((t * 4 + quad) ^ sw) * 4]) = pk;
    }

    __builtin_amdgcn_s_waitcnt(0xC07F);  // lgkmcnt(0) only — vm stays in flight
    __builtin_amdgcn_wave_barrier();

#pragma unroll
    for (int c2 = 0; c2 < 2; ++c2) {
      bf16x8 pf0 = *(const bf16x8*)(&sm.P[w][0][ql * 64 + ((c2 * 8 + quad * 2) ^ sw) * 4]);
      bf16x8 pf1 = *(const bf16x8*)(&sm.P[w][1][ql * 64 + ((c2 * 8 + quad * 2) ^ sw) * 4]);
      o00 = __builtin_amdgcn_mfma_f32_16x16x32_bf16(vf[c2 * 2 + 0], pf0, o00, 0, 0, 0);
      o01 = __builtin_amdgcn_mfma_f32_16x16x32_bf16(vf[c2 * 2 + 1], pf0, o01, 0, 0, 0);
      o10 = __builtin_amdgcn_mfma_f32_16x16x32_bf16(vf[c2 * 2 + 0], pf1, o10, 0, 0, 0);
      o11 = __builtin_amdgcn_mfma_f32_16x16x32_bf16(vf[c2 * 2 + 1], pf1, o11, 0, 0, 0);
    }
    __builtin_amdgcn_wave_barrier();
  };

  for (int it = 0; it < 16; it += 2) {
    int kb0 = kbase + it * 64;
    int kb1 = kbase + ((it + 1) & 15) * 64;
    int kb2 = kbase + ((it + 2) & 15) * 64;
    step(kfa, kfb, kb0, kb1);
    step(kfb, kfa, kb1, kb2);
  }

  float lrun0 = lsv0[0] + lsv0[1] + lsv0[2] + lsv0[3];
  float lrun1 = lsv1[0] + lsv1[1] + lsv1[2] + lsv1[3];
  lrun0 += __shfl_xor(lrun0, 16);
  lrun0 += __shfl_xor(lrun0, 32);
  lrun1 += __shfl_xor(lrun1, 16);
  lrun1 += __shfl_xor(lrun1, 32);

  __syncthreads();  // all waves done with P before epilogue overlay
#pragma unroll
  for (int r = 0; r < 4; ++r) {
    sm.osh[w][0][quad * 4 + r][ql] = o00[r];
    sm.osh[w][0][16 + quad * 4 + r][ql] = o01[r];
    sm.osh[w][1][quad * 4 + r][ql] = o10[r];
    sm.osh[w][1][16 + quad * 4 + r][ql] = o11[r];
  }
  if (quad == 0) {
    lsh[w][0][ql] = lrun0;
    lsh[w][1][ql] = lrun1;
  }
  __syncthreads();

  if (w < 2) {
    int qt = w;
    float l = 0.f;
    f32x4 a0 = {0.f, 0.f, 0.f, 0.f}, a1 = {0.f, 0.f, 0.f, 0.f};
#pragma unroll
    for (int i = 0; i < NW; ++i) {
      l += lsh[i][qt][ql];
#pragma unroll
      for (int r = 0; r < 4; ++r) {
        a0[r] += sm.osh[i][qt][quad * 4 + r][ql];
        a1[r] += sm.osh[i][qt][16 + quad * 4 + r][ql];
      }
    }
    float inv = 1.0f / l;
    s16x4 w0, w1;
#pragma unroll
    for (int r = 0; r < 4; ++r) {
      w0[r] = (short)f2b(a0[r] * inv);
      w1[r] = (short)f2b(a1[r] * inv);
    }
    *(s16x4*)(&Olds[qt][ql][quad * 4]) = w0;
    *(s16x4*)(&Olds[qt][ql][16 + quad * 4]) = w1;
    __builtin_amdgcn_s_waitcnt(0xC07F);
    __builtin_amdgcn_wave_barrier();
    bf16x8 of = *(const bf16x8*)(&Olds[qt][ql][quad * 8]);

    const float* wzr0 = Wz + (size_t)ql * (2 * DM) + ph * DM + quad * 8;
    const float* wzr1 = Wz + (size_t)(ql + 16) * (2 * DM) + ph * DM + quad * 8;
    bf16x8 a0f, a1f;
#pragma unroll
    for (int j = 0; j < 8; ++j) {
      a0f[j] = (short)f2b(wzr0[j]);
      a1f[j] = (short)f2b(wzr1[j]);
    }
    f32x4 z0 = {0.f, 0.f, 0.f, 0.f}, z1 = {0.f, 0.f, 0.f, 0.f};
    if (ph == 0) {
#pragma unroll
      for (int r = 0; r < 4; ++r) {
        z0[r] = bz[quad * 4 + r];
        z1[r] = bz[16 + quad * 4 + r];
      }
    }
    z0 = __builtin_amdgcn_mfma_f32_16x16x32_bf16(a0f, of, z0, 0, 0, 0);
    z1 = __builtin_amdgcn_mfma_f32_16x16x32_bf16(a1f, of, z1, 0, 0, 0);
    int qc = q0 + qt * 16 + ql;
#pragma unroll
    for (int r = 0; r < 4; ++r) {
      Zp[(size_t)(quad * 4 + r) * S + qc] = f2b(z0[r]);
      Zp[(size_t)(16 + quad * 4 + r) * S + qc] = f2b(z1[r]);
    }
  }
}

// ---------------- K3: fused xs-halo + implicit-GEMM MFMA conv + gating ----
// Weight loads now read Wf2 in fragment order: one contiguous 1-KB burst
// per wave per frag (was: 64 scattered 16-B reads at 1728-B row stride).
__global__ __launch_bounds__(256) void conv_mfma_kernel(
    const float* __restrict__ ws, const float* __restrict__ h,
    const float* __restrict__ m, const float* __restrict__ bo,
    float* __restrict__ out) {
  __shared__ unsigned short xt[3][66][104];  // 41184 B
  int bid = blockIdx.x;
  int n = bid >> 7;
  int rem = bid & 127;
  int g = rem & 1;
  int y = rem >> 1;
  int tid = threadIdx.x;
  int wv = tid >> 6;
  int lane = tid & 63;
  int ql = lane & 15, quad = lane >> 4;
  int x0 = wv * 16;

  const unsigned short* Zh = (const unsigned short*)(ws + OFF_ZH) + (size_t)n * DM * S;
  const unsigned short* Zm = (const unsigned short*)(ws + OFF_ZM) + (size_t)n * DM * S;
  const float* hb = h + (size_t)n * CIN * S;
  const unsigned short* Wf = (const unsigned short*)(ws + OFF_WF);

#pragma unroll
  for (int k = 0; k < 36; ++k) {
    int idx = tid + k * 256;
    int xm1 = idx & 63;
    int t2 = idx >> 6;
    int cp = t2 % 48;
    int r3 = t2 / 48;
    int yy = y + r3 - 1;
    unsigned val = 0u;
    if (yy >= 0 && yy < 64) {
      int s = yy * 64 + xm1;
      int ci0 = 2 * cp;
      float a, b;
      if (ci0 < 32) {
        a = b2f(Zh[(size_t)ci0 * S + s]) + b2f(Zm[(size_t)ci0 * S + s]);
        b = b2f(Zh[(size_t)(ci0 + 1) * S + s]) + b2f(Zm[(size_t)(ci0 + 1) * S + s]);
      } else {
        a = hb[(size_t)(ci0 - 32) * S + s];
        b = hb[(size_t)(ci0 - 31) * S + s];
      }
      val = (unsigned)f2b(a) | ((unsigned)f2b(b) << 16);
    }
    *(unsigned*)(&xt[r3][xm1 + 1][2 * cp]) = val;
  }
#pragma unroll
  for (int k = 0; k < 2; ++k) {
    int idx = tid + k * 256;
    if (idx < 288) {
      int r3 = idx / 96;
      int rm = idx % 96;
      int side = rm / 48;
      int cp = rm % 48;
      *(unsigned*)(&xt[r3][side * 65][2 * cp]) = 0u;
    }
  }
  __syncthreads();

  f32x4 acc[6];
#pragma unroll
  for (int t = 0; t < 6; ++t) acc[t] = (f32x4){0.f, 0.f, 0.f, 0.f};

  // frag base for tile j: t12 = (j>>1)*4 + g*2 + (j&1); frag = t12*27 + kb
  const unsigned short* wfb[6];
#pragma unroll
  for (int j = 0; j < 6; ++j) {
    int t12 = (j >> 1) * 4 + g * 2 + (j & 1);
    wfb[j] = Wf + (size_t)t12 * 27 * 512 + lane * 8;
  }

#pragma unroll
  for (int dy = 0; dy < 3; ++dy) {
#pragma unroll
    for (int dx = 0; dx < 3; ++dx) {
      int tap = dy * 3 + dx;
#pragma unroll
      for (int cc = 0; cc < 3; ++cc) {
        bf16x8 b = *(const bf16x8*)(&xt[dy][x0 + ql + dx][cc * 32 + quad * 8]);
        int kb = tap * 3 + cc;
#pragma unroll
        for (int j = 0; j < 6; ++j) {
          bf16x8 wf = *(const bf16x8*)(wfb[j] + (size_t)kb * 512);
          acc[j] = __builtin_amdgcn_mfma_f32_16x16x32_bf16(wf, b, acc[j], 0, 0, 0);
        }
      }
    }
  }

  int s = y * 64 + x0 + ql;
#pragma unroll
  for (int jj = 0; jj < 2; ++jj) {
#pragma unroll
    for (int r = 0; r < 4; ++r) {
      int c = g * 32 + jj * 16 + quad * 4 + r;
      float iv = acc[jj][r] + bo[c];
      float gv = acc[2 + jj][r] + bo[64 + c];
      float ov = acc[4 + jj][r] + bo[128 + c];
      float ig = 1.f / (1.f + __expf(-iv));
      float gg = tanhf(gv);
      float og = 1.f / (1.f + __expf(-ov));
      size_t oidx = (((size_t)n * 64 + c) << 12) + s;
      float mold = m[oidx];
      float mn = ig * gg + (1.f - ig) * mold;
      out[oidx] = og * mn;
      out[(size_t)NB * CIN * S + oidx] = mn;
    }
  }
}

extern "C" void kernel_launch(void* const* d_in, const int* in_sizes, int n_in,
                              void* d_out, int out_size, void* d_ws, size_t ws_size,
                              hipStream_t stream) {
  const float* h = (const float*)d_in[0];
  const float* m = (const float*)d_in[1];
  const float* Wh = (const float*)d_in[2];
  const float* bh = (const float*)d_in[3];
  const float* Wm = (const float*)d_in[4];
  const float* bm = (const float*)d_in[5];
  const float* Wz = (const float*)d_in[6];
  const float* bz = (const float*)d_in[7];
  const float* Wo = (const float*)d_in[8];
  const float* bo = (const float*)d_in[9];
  float* out = (float*)d_out;
  float* ws = (float*)d_ws;

  prep_kernel<<<836, 256, 0, stream>>>(h, m, Wh, bh, Wm, bm, Wo, ws);
  attn_kernel<<<2 * NB * (S / 32), 256, 0, stream>>>(ws, Wz, bz);
  conv_mfma_kernel<<<NB * 128, 256, 0, stream>>>(ws, h, m, bo, out);
}

// Round 13
// 170.293 us; speedup vs baseline: 1.2882x; 1.0864x over previous
//
#include <hip/hip_runtime.h>
#include <math.h>

#define NB 4
#define CIN 64
#define DM 32
#define S 4096
#define NW 4

// ws float-offsets (~7.7 MB; under the 8 MB proven in round 2)
#define OFF_Q  0          // bf16 [n][s][32]  (scaled by log2e/sqrt(32))
#define OFF_KH 262144     // bf16 [n][s][32]
#define OFF_VH 524288     // bf16 [n][c][s]
#define OFF_KM 786432     // bf16 [n][s][32]
#define OFF_VM 1048576    // bf16 [n][c][s]
#define OFF_ZH 1310720    // bf16 [n][32][s]
#define OFF_ZM 1572864    // bf16 [n][32][s]
#define OFF_WF 1835008    // bf16 Wf2[324 frags][64 lanes][8]  (A-frag order)

typedef __attribute__((ext_vector_type(8))) short bf16x8;
typedef __attribute__((ext_vector_type(4))) short s16x4;
typedef __attribute__((ext_vector_type(4))) float f32x4;
typedef __attribute__((ext_vector_type(2))) unsigned int u32x2;
typedef __attribute__((ext_vector_type(4))) unsigned int u32x4;

__device__ inline unsigned short f2b(float x) {
  union { float f; unsigned u; } v;
  v.f = x;
  unsigned r = (v.u + 0x7FFF + ((v.u >> 16) & 1)) >> 16;
  return (unsigned short)r;
}

__device__ inline float b2f(unsigned short u) {
  union { unsigned u; float f; } v;
  v.u = ((unsigned)u) << 16;
  return v.f;
}

__device__ inline unsigned fbits(float x) {
  union { float f; unsigned u; } v;
  v.f = x;
  return v.u;
}

// ---------------- K1: fused prep: proj(h), proj(m), wprep ----------------
// Weight rows are wave-uniform; readfirstlane makes that provable to the
// compiler so w[] loads become s_load bursts (they were 1536 per-lane
// broadcast VMEM loads per wave — the hidden cost of rounds 8-12).
__global__ __launch_bounds__(256) void prep_kernel(
    const float* __restrict__ h, const float* __restrict__ m,
    const float* __restrict__ Wh, const float* __restrict__ bh,
    const float* __restrict__ Wm, const float* __restrict__ bm,
    const float* __restrict__ Wo, float* __restrict__ ws) {
  __shared__ unsigned short sm[64][34];
  int bid = blockIdx.x;
  int tid = threadIdx.x;

  if (bid >= 512) {  // ---- wprep: Wf2 in MFMA A-frag order, 82944 uints
    int idx = (bid - 512) * 256 + tid;
    int f = idx >> 8;
    int r = idx & 255;
    int lane = r >> 2;
    int jp = (r & 3) * 2;
    int ql = lane & 15, quad = lane >> 4;
    int co = (f / 27) * 16 + ql;
    int k = (f % 27) * 32 + quad * 8 + jp;
    int tap = k / 96;
    int ci = k - tap * 96;
    float a = Wo[((size_t)co * 96 + ci) * 9 + tap];
    float b = Wo[((size_t)co * 96 + ci + 1) * 9 + tap];
    unsigned val = (unsigned)f2b(a) | ((unsigned)f2b(b) << 16);
    ((unsigned*)(ws + OFF_WF))[idx] = val;
    return;
  }

  int mode = (bid >= 256) ? 1 : 0;
  const float* in = mode ? m : h;
  const float* W = mode ? Wm : Wh;
  const float* b = mode ? bm : bh;
  int lbid = bid & 255;
  int n = lbid >> 6;
  int s0 = (lbid & 63) * 64;
  int sl = tid & 63;
  int cg = tid >> 6;
  const float* inp = in + (size_t)n * CIN * S + s0 + sl;

  float reg[64];
#pragma unroll
  for (int ci = 0; ci < 64; ++ci) reg[ci] = inp[(size_t)ci * S];

  float acc[24];
  int na = (mode == 0) ? 24 : 16;
  if (mode == 0) {
#pragma unroll
    for (int k = 0; k < 24; ++k) {
      int co = __builtin_amdgcn_readfirstlane(cg + k * 4);  // wave-uniform
      const float* w = W + (size_t)co * CIN;
      float a = b[co];
#pragma unroll
      for (int ci = 0; ci < CIN; ++ci) a += w[ci] * reg[ci];
      acc[k] = a;
    }
  } else {
#pragma unroll
    for (int k = 0; k < 16; ++k) {
      int co = __builtin_amdgcn_readfirstlane(cg + k * 4);  // wave-uniform
      const float* w = W + (size_t)co * CIN;
      float a = b[co];
#pragma unroll
      for (int ci = 0; ci < CIN; ++ci) a += w[ci] * reg[ci];
      acc[k] = a;
    }
  }
  (void)na;

  unsigned short* qsl = (unsigned short*)(ws + OFF_Q);
  unsigned short* khs = (unsigned short*)(ws + OFF_KH);
  unsigned short* vhs = (unsigned short*)(ws + OFF_VH);
  unsigned short* kms = (unsigned short*)(ws + OFF_KM);
  unsigned short* vms = (unsigned short*)(ws + OFF_VM);

  int ngrp = (mode == 0) ? 2 : 1;
  for (int g = 0; g < ngrp; ++g) {
    __syncthreads();
    const float rs = 0.2550400330665387f;  // log2e / sqrt(32)
#pragma unroll
    for (int j = 0; j < 8; ++j) {
      int k = g * 8 + j;
      int c = cg + 4 * j;
      float v = acc[k];
      if (mode == 0 && g == 0) v *= rs;
      sm[sl][c] = f2b(v);
    }
    __syncthreads();
    unsigned short* dst;
    if (mode == 0)
      dst = (g == 0 ? qsl : khs);
    else
      dst = kms;
    unsigned* du = (unsigned*)(dst + ((size_t)n * S + s0) * 32);
#pragma unroll
    for (int i = 0; i < 4; ++i) {
      int idx = tid + i * 256;
      int s = idx >> 4, cp = idx & 15;
      unsigned val = (unsigned)sm[s][2 * cp] | ((unsigned)sm[s][2 * cp + 1] << 16);
      du[idx] = val;
    }
  }
  int k0 = (mode == 0) ? 16 : 8;
  unsigned short* vdst = (mode == 0) ? vhs : vms;
#pragma unroll
  for (int j = 0; j < 8; ++j) {
    int k = k0 + j;
    int c = cg + 4 * j;
    vdst[((size_t)n * DM + c) * S + s0 + sl] = f2b(acc[k]);
  }
}

// ---------------- K2: MFMA flash attention, K-split x4 (round-10 exact) ---
union AttnSmem {
  unsigned short P[NW][2][1024];   // [wave][qtile][16 rows x 64 keys]
  float osh[NW][2][32][16];        // merge partials — epilogue overlay
};

__global__ __launch_bounds__(256, 4) void attn_kernel(
    float* __restrict__ ws, const float* __restrict__ Wz,
    const float* __restrict__ bz) {
  __shared__ __align__(16) AttnSmem sm;
  __shared__ float lsh[NW][2][16];
  __shared__ unsigned short Olds[2][16][40];

  int bid = blockIdx.x;
  int ph = bid & 1;
  int n = (bid >> 1) & 3;
  int q0 = (bid >> 3) * 32;
  int tid = threadIdx.x;
  int w = tid >> 6;
  int lane = tid & 63;
  int ql = lane & 15;
  int quad = lane >> 4;
  int kbase = w * 1024;
  int sw = 2 * (ql & 7);           // granule XOR swizzle (even)

  const unsigned short* qs = (const unsigned short*)(ws + OFF_Q) + ((size_t)n * S + q0) * 32;
  const unsigned short* Ks = (const unsigned short*)(ws + (ph ? OFF_KM : OFF_KH)) + (size_t)n * S * 32;
  const unsigned short* Vs = (const unsigned short*)(ws + (ph ? OFF_VM : OFF_VH)) + (size_t)n * DM * S;
  unsigned short* Zp = (unsigned short*)(ws + (ph ? OFF_ZM : OFF_ZH)) + (size_t)n * DM * S;

  bf16x8 qf0 = *(const bf16x8*)(qs + ql * 32 + quad * 8);
  bf16x8 qf1 = *(const bf16x8*)(qs + (16 + ql) * 32 + quad * 8);

  f32x4 o00 = {0.f, 0.f, 0.f, 0.f}, o01 = {0.f, 0.f, 0.f, 0.f};
  f32x4 o10 = {0.f, 0.f, 0.f, 0.f}, o11 = {0.f, 0.f, 0.f, 0.f};
  f32x4 lsv0 = {0.f, 0.f, 0.f, 0.f}, lsv1 = {0.f, 0.f, 0.f, 0.f};
  const float ZI = -11.541560327111707f;  // -8 * log2(e)
  const f32x4 zinit = {ZI, ZI, ZI, ZI};

  bf16x8 kfa[4], kfb[4];
#pragma unroll
  for (int t = 0; t < 4; ++t)
    kfa[t] = *(const bf16x8*)(Ks + (size_t)(kbase + t * 16 + ql) * 32 + quad * 8);

  auto step = [&](bf16x8 (&kfc)[4], bf16x8 (&kfn)[4], int kb, int kbn) {
    bf16x8 vf[4];
#pragma unroll
    for (int c2 = 0; c2 < 2; ++c2)
#pragma unroll
      for (int t2 = 0; t2 < 2; ++t2)
        vf[c2 * 2 + t2] = *(const bf16x8*)(Vs + (size_t)(t2 * 16 + ql) * S + kb + c2 * 32 + quad * 8);
#pragma unroll
    for (int t = 0; t < 4; ++t)
      kfn[t] = *(const bf16x8*)(Ks + (size_t)(kbn + t * 16 + ql) * 32 + quad * 8);

#pragma unroll
    for (int t = 0; t < 4; ++t) {
      f32x4 stt = __builtin_amdgcn_mfma_f32_16x16x32_bf16(kfc[t], qf0, zinit, 0, 0, 0);
      f32x4 e;
#pragma unroll
      for (int r = 0; r < 4; ++r) e[r] = __builtin_amdgcn_exp2f(stt[r]);
      lsv0 += e;
      u32x2 pk;
      pk[0] = __builtin_amdgcn_perm(fbits(e[1]), fbits(e[0]), 0x07060302u);
      pk[1] = __builtin_amdgcn_perm(fbits(e[3]), fbits(e[2]), 0x07060302u);
      *(u32x2*)(&sm.P[w][0][ql * 64 + ((t * 4 + quad) ^ sw) * 4]) = pk;
    }
#pragma unroll
    for (int t = 0; t < 4; ++t) {
      f32x4 stt = __builtin_amdgcn_mfma_f32_16x16x32_bf16(kfc[t], qf1, zinit, 0, 0, 0);
      f32x4 e;
#pragma unroll
      for (int r = 0; r < 4; ++r) e[r] = __builtin_amdgcn_exp2f(stt[r]);
      lsv1 += e;
      u32x2 pk;
      pk[0] = __builtin_amdgcn_perm(fbits(e[1]), fbits(e[0]), 0x07060302u);
      pk[1] = __builtin_amdgcn_perm(fbits(e[3]), fbits(e[2]), 0x07060302u);
      *(u32x2*)(&sm.P[w][1][ql * 64 + ((t * 4 + quad) ^ sw) * 4]) = pk;
    }

    __builtin_amdgcn_s_waitcnt(0xC07F);  // lgkmcnt(0) only — vm stays in flight
    __builtin_amdgcn_wave_barrier();

#pragma unroll
    for (int c2 = 0; c2 < 2; ++c2) {
      bf16x8 pf0 = *(const bf16x8*)(&sm.P[w][0][ql * 64 + ((c2 * 8 + quad * 2) ^ sw) * 4]);
      bf16x8 pf1 = *(const bf16x8*)(&sm.P[w][1][ql * 64 + ((c2 * 8 + quad * 2) ^ sw) * 4]);
      o00 = __builtin_amdgcn_mfma_f32_16x16x32_bf16(vf[c2 * 2 + 0], pf0, o00, 0, 0, 0);
      o01 = __builtin_amdgcn_mfma_f32_16x16x32_bf16(vf[c2 * 2 + 1], pf0, o01, 0, 0, 0);
      o10 = __builtin_amdgcn_mfma_f32_16x16x32_bf16(vf[c2 * 2 + 0], pf1, o10, 0, 0, 0);
      o11 = __builtin_amdgcn_mfma_f32_16x16x32_bf16(vf[c2 * 2 + 1], pf1, o11, 0, 0, 0);
    }
    __builtin_amdgcn_wave_barrier();
  };

  for (int it = 0; it < 16; it += 2) {
    int kb0 = kbase + it * 64;
    int kb1 = kbase + ((it + 1) & 15) * 64;
    int kb2 = kbase + ((it + 2) & 15) * 64;
    step(kfa, kfb, kb0, kb1);
    step(kfb, kfa, kb1, kb2);
  }

  float lrun0 = lsv0[0] + lsv0[1] + lsv0[2] + lsv0[3];
  float lrun1 = lsv1[0] + lsv1[1] + lsv1[2] + lsv1[3];
  lrun0 += __shfl_xor(lrun0, 16);
  lrun0 += __shfl_xor(lrun0, 32);
  lrun1 += __shfl_xor(lrun1, 16);
  lrun1 += __shfl_xor(lrun1, 32);

  __syncthreads();  // all waves done with P before epilogue overlay
#pragma unroll
  for (int r = 0; r < 4; ++r) {
    sm.osh[w][0][quad * 4 + r][ql] = o00[r];
    sm.osh[w][0][16 + quad * 4 + r][ql] = o01[r];
    sm.osh[w][1][quad * 4 + r][ql] = o10[r];
    sm.osh[w][1][16 + quad * 4 + r][ql] = o11[r];
  }
  if (quad == 0) {
    lsh[w][0][ql] = lrun0;
    lsh[w][1][ql] = lrun1;
  }
  __syncthreads();

  if (w < 2) {
    int qt = w;
    float l = 0.f;
    f32x4 a0 = {0.f, 0.f, 0.f, 0.f}, a1 = {0.f, 0.f, 0.f, 0.f};
#pragma unroll
    for (int i = 0; i < NW; ++i) {
      l += lsh[i][qt][ql];
#pragma unroll
      for (int r = 0; r < 4; ++r) {
        a0[r] += sm.osh[i][qt][quad * 4 + r][ql];
        a1[r] += sm.osh[i][qt][16 + quad * 4 + r][ql];
      }
    }
    float inv = 1.0f / l;
    s16x4 w0, w1;
#pragma unroll
    for (int r = 0; r < 4; ++r) {
      w0[r] = (short)f2b(a0[r] * inv);
      w1[r] = (short)f2b(a1[r] * inv);
    }
    *(s16x4*)(&Olds[qt][ql][quad * 4]) = w0;
    *(s16x4*)(&Olds[qt][ql][16 + quad * 4]) = w1;
    __builtin_amdgcn_s_waitcnt(0xC07F);
    __builtin_amdgcn_wave_barrier();
    bf16x8 of = *(const bf16x8*)(&Olds[qt][ql][quad * 8]);

    const float* wzr0 = Wz + (size_t)ql * (2 * DM) + ph * DM + quad * 8;
    const float* wzr1 = Wz + (size_t)(ql + 16) * (2 * DM) + ph * DM + quad * 8;
    bf16x8 a0f, a1f;
#pragma unroll
    for (int j = 0; j < 8; ++j) {
      a0f[j] = (short)f2b(wzr0[j]);
      a1f[j] = (short)f2b(wzr1[j]);
    }
    f32x4 z0 = {0.f, 0.f, 0.f, 0.f}, z1 = {0.f, 0.f, 0.f, 0.f};
    if (ph == 0) {
#pragma unroll
      for (int r = 0; r < 4; ++r) {
        z0[r] = bz[quad * 4 + r];
        z1[r] = bz[16 + quad * 4 + r];
      }
    }
    z0 = __builtin_amdgcn_mfma_f32_16x16x32_bf16(a0f, of, z0, 0, 0, 0);
    z1 = __builtin_amdgcn_mfma_f32_16x16x32_bf16(a1f, of, z1, 0, 0, 0);
    int qc = q0 + qt * 16 + ql;
#pragma unroll
    for (int r = 0; r < 4; ++r) {
      Zp[(size_t)(quad * 4 + r) * S + qc] = f2b(z0[r]);
      Zp[(size_t)(16 + quad * 4 + r) * S + qc] = f2b(z1[r]);
    }
  }
}

// ---------------- K3: fused xs-halo + implicit-GEMM MFMA conv + gating ----
// Halo fill now writes b128 per thread (8 channels): 9 iters instead of 36
// uint writes; b128 spans all 32 banks (the uint writes at 52-word lane
// stride hit only 8 banks -> 8-way conflict).
__global__ __launch_bounds__(256) void conv_mfma_kernel(
    const float* __restrict__ ws, const float* __restrict__ h,
    const float* __restrict__ m, const float* __restrict__ bo,
    float* __restrict__ out) {
  __shared__ unsigned short xt[3][66][104];  // 41184 B
  int bid = blockIdx.x;
  int n = bid >> 7;
  int rem = bid & 127;
  int g = rem & 1;
  int y = rem >> 1;
  int tid = threadIdx.x;
  int wv = tid >> 6;
  int lane = tid & 63;
  int ql = lane & 15, quad = lane >> 4;
  int x0 = wv * 16;

  const unsigned short* Zh = (const unsigned short*)(ws + OFF_ZH) + (size_t)n * DM * S;
  const unsigned short* Zm = (const unsigned short*)(ws + OFF_ZM) + (size_t)n * DM * S;
  const float* hb = h + (size_t)n * CIN * S;
  const unsigned short* Wf = (const unsigned short*)(ws + OFF_WF);

  // halo: 3 rows x 64 x x 12 blocks-of-8ci = 2304 b128 writes
#pragma unroll
  for (int k = 0; k < 9; ++k) {
    int idx = tid + k * 256;
    int xm1 = idx & 63;
    int t2 = idx >> 6;         // 0..35
    int cb = t2 % 12;
    int r3 = t2 / 12;
    int yy = y + r3 - 1;
    u32x4 val = {0u, 0u, 0u, 0u};
    if (yy >= 0 && yy < 64) {
      int s = yy * 64 + xm1;
      int ci0 = cb * 8;
      float a[8];
      if (ci0 < 32) {
#pragma unroll
        for (int j = 0; j < 8; ++j)
          a[j] = b2f(Zh[(size_t)(ci0 + j) * S + s]) + b2f(Zm[(size_t)(ci0 + j) * S + s]);
      } else {
#pragma unroll
        for (int j = 0; j < 8; ++j)
          a[j] = hb[(size_t)(ci0 - 32 + j) * S + s];
      }
#pragma unroll
      for (int t = 0; t < 4; ++t)
        val[t] = (unsigned)f2b(a[2 * t]) | ((unsigned)f2b(a[2 * t + 1]) << 16);
    }
    *(u32x4*)(&xt[r3][xm1 + 1][cb * 8]) = val;
  }
  // x guard columns: 3 r3 x 2 sides x 12 cb = 72 b128 writes
  if (tid < 72) {
    int r3 = tid / 24;
    int rm = tid % 24;
    int side = rm / 12;
    int cb = rm % 12;
    *(u32x4*)(&xt[r3][side * 65][cb * 8]) = (u32x4){0u, 0u, 0u, 0u};
  }
  __syncthreads();

  f32x4 acc[6];
#pragma unroll
  for (int t = 0; t < 6; ++t) acc[t] = (f32x4){0.f, 0.f, 0.f, 0.f};

  const unsigned short* wfb[6];
#pragma unroll
  for (int j = 0; j < 6; ++j) {
    int t12 = (j >> 1) * 4 + g * 2 + (j & 1);
    wfb[j] = Wf + (size_t)t12 * 27 * 512 + lane * 8;
  }

#pragma unroll
  for (int dy = 0; dy < 3; ++dy) {
#pragma unroll
    for (int dx = 0; dx < 3; ++dx) {
      int tap = dy * 3 + dx;
#pragma unroll
      for (int cc = 0; cc < 3; ++cc) {
        bf16x8 b = *(const bf16x8*)(&xt[dy][x0 + ql + dx][cc * 32 + quad * 8]);
        int kb = tap * 3 + cc;
#pragma unroll
        for (int j = 0; j < 6; ++j) {
          bf16x8 wf = *(const bf16x8*)(wfb[j] + (size_t)kb * 512);
          acc[j] = __builtin_amdgcn_mfma_f32_16x16x32_bf16(wf, b, acc[j], 0, 0, 0);
        }
      }
    }
  }

  int s = y * 64 + x0 + ql;
#pragma unroll
  for (int jj = 0; jj < 2; ++jj) {
#pragma unroll
    for (int r = 0; r < 4; ++r) {
      int c = g * 32 + jj * 16 + quad * 4 + r;
      float iv = acc[jj][r] + bo[c];
      float gv = acc[2 + jj][r] + bo[64 + c];
      float ov = acc[4 + jj][r] + bo[128 + c];
      float ig = 1.f / (1.f + __expf(-iv));
      float gg = tanhf(gv);
      float og = 1.f / (1.f + __expf(-ov));
      size_t oidx = (((size_t)n * 64 + c) << 12) + s;
      float mold = m[oidx];
      float mn = ig * gg + (1.f - ig) * mold;
      out[oidx] = og * mn;
      out[(size_t)NB * CIN * S + oidx] = mn;
    }
  }
}

extern "C" void kernel_launch(void* const* d_in, const int* in_sizes, int n_in,
                              void* d_out, int out_size, void* d_ws, size_t ws_size,
                              hipStream_t stream) {
  const float* h = (const float*)d_in[0];
  const float* m = (const float*)d_in[1];
  const float* Wh = (const float*)d_in[2];
  const float* bh = (const float*)d_in[3];
  const float* Wm = (const float*)d_in[4];
  const float* bm = (const float*)d_in[5];
  const float* Wz = (const float*)d_in[6];
  const float* bz = (const float*)d_in[7];
  const float* Wo = (const float*)d_in[8];
  const float* bo = (const float*)d_in[9];
  float* out = (float*)d_out;
  float* ws = (float*)d_ws;

  prep_kernel<<<836, 256, 0, stream>>>(h, m, Wh, bh, Wm, bm, Wo, ws);
  attn_kernel<<<2 * NB * (S / 32), 256, 0, stream>>>(ws, Wz, bz);
  conv_mfma_kernel<<<NB * 128, 256, 0, stream>>>(ws, h, m, bo, out);
}

// Round 14
// 161.036 us; speedup vs baseline: 1.3623x; 1.0575x over previous
//
#include <hip/hip_runtime.h>
#include <math.h>

#define NB 4
#define CIN 64
#define DM 32
#define S 4096
#define NW 4

// ws float-offsets (~7.7 MB; under the 8 MB proven in round 2)
#define OFF_Q  0          // bf16 [n][s][32]  (scaled by log2e/sqrt(32))
#define OFF_KH 262144     // bf16 [n][s][32]
#define OFF_VH 524288     // bf16 [n][c][s]
#define OFF_KM 786432     // bf16 [n][s][32]
#define OFF_VM 1048576    // bf16 [n][c][s]
#define OFF_ZH 1310720    // bf16 [n][32][s]
#define OFF_ZM 1572864    // bf16 [n][32][s]
#define OFF_WF 1835008    // bf16 Wf2[324 frags][64 lanes][8]  (A-frag order)

typedef __attribute__((ext_vector_type(8))) short bf16x8;
typedef __attribute__((ext_vector_type(4))) short s16x4;
typedef __attribute__((ext_vector_type(4))) float f32x4;
typedef __attribute__((ext_vector_type(2))) unsigned int u32x2;
typedef __attribute__((ext_vector_type(4))) unsigned int u32x4;

__device__ inline unsigned short f2b(float x) {
  union { float f; unsigned u; } v;
  v.f = x;
  unsigned r = (v.u + 0x7FFF + ((v.u >> 16) & 1)) >> 16;
  return (unsigned short)r;
}

__device__ inline float b2f(unsigned short u) {
  union { unsigned u; float f; } v;
  v.u = ((unsigned)u) << 16;
  return v.f;
}

__device__ inline unsigned fbits(float x) {
  union { float f; unsigned u; } v;
  v.f = x;
  return v.u;
}

// ---------------- K1: fused prep: proj(h), proj(m), wprep ----------------
__global__ __launch_bounds__(256) void prep_kernel(
    const float* __restrict__ h, const float* __restrict__ m,
    const float* __restrict__ Wh, const float* __restrict__ bh,
    const float* __restrict__ Wm, const float* __restrict__ bm,
    const float* __restrict__ Wo, float* __restrict__ ws) {
  __shared__ unsigned short sm[64][34];
  int bid = blockIdx.x;
  int tid = threadIdx.x;

  if (bid >= 512) {  // ---- wprep: Wf2 in MFMA A-frag order, 82944 uints
    int idx = (bid - 512) * 256 + tid;
    int f = idx >> 8;
    int r = idx & 255;
    int lane = r >> 2;
    int jp = (r & 3) * 2;
    int ql = lane & 15, quad = lane >> 4;
    int co = (f / 27) * 16 + ql;
    int k = (f % 27) * 32 + quad * 8 + jp;
    int tap = k / 96;
    int ci = k - tap * 96;
    float a = Wo[((size_t)co * 96 + ci) * 9 + tap];
    float b = Wo[((size_t)co * 96 + ci + 1) * 9 + tap];
    unsigned val = (unsigned)f2b(a) | ((unsigned)f2b(b) << 16);
    ((unsigned*)(ws + OFF_WF))[idx] = val;
    return;
  }

  int mode = (bid >= 256) ? 1 : 0;
  const float* in = mode ? m : h;
  const float* W = mode ? Wm : Wh;
  const float* b = mode ? bm : bh;
  int lbid = bid & 255;
  int n = lbid >> 6;
  int s0 = (lbid & 63) * 64;
  int sl = tid & 63;
  int cg = tid >> 6;
  const float* inp = in + (size_t)n * CIN * S + s0 + sl;

  float reg[64];
#pragma unroll
  for (int ci = 0; ci < 64; ++ci) reg[ci] = inp[(size_t)ci * S];

  float acc[24];
  if (mode == 0) {
#pragma unroll
    for (int k = 0; k < 24; ++k) {
      int co = __builtin_amdgcn_readfirstlane(cg + k * 4);  // wave-uniform
      const float* w = W + (size_t)co * CIN;
      float a = b[co];
#pragma unroll
      for (int ci = 0; ci < CIN; ++ci) a += w[ci] * reg[ci];
      acc[k] = a;
    }
  } else {
#pragma unroll
    for (int k = 0; k < 16; ++k) {
      int co = __builtin_amdgcn_readfirstlane(cg + k * 4);  // wave-uniform
      const float* w = W + (size_t)co * CIN;
      float a = b[co];
#pragma unroll
      for (int ci = 0; ci < CIN; ++ci) a += w[ci] * reg[ci];
      acc[k] = a;
    }
  }

  unsigned short* qsl = (unsigned short*)(ws + OFF_Q);
  unsigned short* khs = (unsigned short*)(ws + OFF_KH);
  unsigned short* vhs = (unsigned short*)(ws + OFF_VH);
  unsigned short* kms = (unsigned short*)(ws + OFF_KM);
  unsigned short* vms = (unsigned short*)(ws + OFF_VM);

  int ngrp = (mode == 0) ? 2 : 1;
  for (int g = 0; g < ngrp; ++g) {
    __syncthreads();
    const float rs = 0.2550400330665387f;  // log2e / sqrt(32)
#pragma unroll
    for (int j = 0; j < 8; ++j) {
      int k = g * 8 + j;
      int c = cg + 4 * j;
      float v = acc[k];
      if (mode == 0 && g == 0) v *= rs;
      sm[sl][c] = f2b(v);
    }
    __syncthreads();
    unsigned short* dst;
    if (mode == 0)
      dst = (g == 0 ? qsl : khs);
    else
      dst = kms;
    unsigned* du = (unsigned*)(dst + ((size_t)n * S + s0) * 32);
#pragma unroll
    for (int i = 0; i < 4; ++i) {
      int idx = tid + i * 256;
      int s = idx >> 4, cp = idx & 15;
      unsigned val = (unsigned)sm[s][2 * cp] | ((unsigned)sm[s][2 * cp + 1] << 16);
      du[idx] = val;
    }
  }
  int k0 = (mode == 0) ? 16 : 8;
  unsigned short* vdst = (mode == 0) ? vhs : vms;
#pragma unroll
  for (int j = 0; j < 8; ++j) {
    int k = k0 + j;
    int c = cg + 4 * j;
    vdst[((size_t)n * DM + c) * S + s0 + sl] = f2b(acc[k]);
  }
}

// ---------------- K2: MFMA flash attention, K-split x4 (round-10 exact) ---
union AttnSmem {
  unsigned short P[NW][2][1024];   // [wave][qtile][16 rows x 64 keys]
  float osh[NW][2][32][16];        // merge partials — epilogue overlay
};

__global__ __launch_bounds__(256, 4) void attn_kernel(
    float* __restrict__ ws, const float* __restrict__ Wz,
    const float* __restrict__ bz) {
  __shared__ __align__(16) AttnSmem sm;
  __shared__ float lsh[NW][2][16];
  __shared__ unsigned short Olds[2][16][40];

  int bid = blockIdx.x;
  int ph = bid & 1;
  int n = (bid >> 1) & 3;
  int q0 = (bid >> 3) * 32;
  int tid = threadIdx.x;
  int w = tid >> 6;
  int lane = tid & 63;
  int ql = lane & 15;
  int quad = lane >> 4;
  int kbase = w * 1024;
  int sw = 2 * (ql & 7);           // granule XOR swizzle (even)

  const unsigned short* qs = (const unsigned short*)(ws + OFF_Q) + ((size_t)n * S + q0) * 32;
  const unsigned short* Ks = (const unsigned short*)(ws + (ph ? OFF_KM : OFF_KH)) + (size_t)n * S * 32;
  const unsigned short* Vs = (const unsigned short*)(ws + (ph ? OFF_VM : OFF_VH)) + (size_t)n * DM * S;
  unsigned short* Zp = (unsigned short*)(ws + (ph ? OFF_ZM : OFF_ZH)) + (size_t)n * DM * S;

  bf16x8 qf0 = *(const bf16x8*)(qs + ql * 32 + quad * 8);
  bf16x8 qf1 = *(const bf16x8*)(qs + (16 + ql) * 32 + quad * 8);

  f32x4 o00 = {0.f, 0.f, 0.f, 0.f}, o01 = {0.f, 0.f, 0.f, 0.f};
  f32x4 o10 = {0.f, 0.f, 0.f, 0.f}, o11 = {0.f, 0.f, 0.f, 0.f};
  f32x4 lsv0 = {0.f, 0.f, 0.f, 0.f}, lsv1 = {0.f, 0.f, 0.f, 0.f};
  const float ZI = -11.541560327111707f;  // -8 * log2(e)
  const f32x4 zinit = {ZI, ZI, ZI, ZI};

  bf16x8 kfa[4], kfb[4];
#pragma unroll
  for (int t = 0; t < 4; ++t)
    kfa[t] = *(const bf16x8*)(Ks + (size_t)(kbase + t * 16 + ql) * 32 + quad * 8);

  auto step = [&](bf16x8 (&kfc)[4], bf16x8 (&kfn)[4], int kb, int kbn) {
    bf16x8 vf[4];
#pragma unroll
    for (int c2 = 0; c2 < 2; ++c2)
#pragma unroll
      for (int t2 = 0; t2 < 2; ++t2)
        vf[c2 * 2 + t2] = *(const bf16x8*)(Vs + (size_t)(t2 * 16 + ql) * S + kb + c2 * 32 + quad * 8);
#pragma unroll
    for (int t = 0; t < 4; ++t)
      kfn[t] = *(const bf16x8*)(Ks + (size_t)(kbn + t * 16 + ql) * 32 + quad * 8);

#pragma unroll
    for (int t = 0; t < 4; ++t) {
      f32x4 stt = __builtin_amdgcn_mfma_f32_16x16x32_bf16(kfc[t], qf0, zinit, 0, 0, 0);
      f32x4 e;
#pragma unroll
      for (int r = 0; r < 4; ++r) e[r] = __builtin_amdgcn_exp2f(stt[r]);
      lsv0 += e;
      u32x2 pk;
      pk[0] = __builtin_amdgcn_perm(fbits(e[1]), fbits(e[0]), 0x07060302u);
      pk[1] = __builtin_amdgcn_perm(fbits(e[3]), fbits(e[2]), 0x07060302u);
      *(u32x2*)(&sm.P[w][0][ql * 64 + ((t * 4 + quad) ^ sw) * 4]) = pk;
    }
#pragma unroll
    for (int t = 0; t < 4; ++t) {
      f32x4 stt = __builtin_amdgcn_mfma_f32_16x16x32_bf16(kfc[t], qf1, zinit, 0, 0, 0);
      f32x4 e;
#pragma unroll
      for (int r = 0; r < 4; ++r) e[r] = __builtin_amdgcn_exp2f(stt[r]);
      lsv1 += e;
      u32x2 pk;
      pk[0] = __builtin_amdgcn_perm(fbits(e[1]), fbits(e[0]), 0x07060302u);
      pk[1] = __builtin_amdgcn_perm(fbits(e[3]), fbits(e[2]), 0x07060302u);
      *(u32x2*)(&sm.P[w][1][ql * 64 + ((t * 4 + quad) ^ sw) * 4]) = pk;
    }

    __builtin_amdgcn_s_waitcnt(0xC07F);  // lgkmcnt(0) only — vm stays in flight
    __builtin_amdgcn_wave_barrier();

#pragma unroll
    for (int c2 = 0; c2 < 2; ++c2) {
      bf16x8 pf0 = *(const bf16x8*)(&sm.P[w][0][ql * 64 + ((c2 * 8 + quad * 2) ^ sw) * 4]);
      bf16x8 pf1 = *(const bf16x8*)(&sm.P[w][1][ql * 64 + ((c2 * 8 + quad * 2) ^ sw) * 4]);
      o00 = __builtin_amdgcn_mfma_f32_16x16x32_bf16(vf[c2 * 2 + 0], pf0, o00, 0, 0, 0);
      o01 = __builtin_amdgcn_mfma_f32_16x16x32_bf16(vf[c2 * 2 + 1], pf0, o01, 0, 0, 0);
      o10 = __builtin_amdgcn_mfma_f32_16x16x32_bf16(vf[c2 * 2 + 0], pf1, o10, 0, 0, 0);
      o11 = __builtin_amdgcn_mfma_f32_16x16x32_bf16(vf[c2 * 2 + 1], pf1, o11, 0, 0, 0);
    }
    __builtin_amdgcn_wave_barrier();
  };

  for (int it = 0; it < 16; it += 2) {
    int kb0 = kbase + it * 64;
    int kb1 = kbase + ((it + 1) & 15) * 64;
    int kb2 = kbase + ((it + 2) & 15) * 64;
    step(kfa, kfb, kb0, kb1);
    step(kfb, kfa, kb1, kb2);
  }

  float lrun0 = lsv0[0] + lsv0[1] + lsv0[2] + lsv0[3];
  float lrun1 = lsv1[0] + lsv1[1] + lsv1[2] + lsv1[3];
  lrun0 += __shfl_xor(lrun0, 16);
  lrun0 += __shfl_xor(lrun0, 32);
  lrun1 += __shfl_xor(lrun1, 16);
  lrun1 += __shfl_xor(lrun1, 32);

  __syncthreads();  // all waves done with P before epilogue overlay
#pragma unroll
  for (int r = 0; r < 4; ++r) {
    sm.osh[w][0][quad * 4 + r][ql] = o00[r];
    sm.osh[w][0][16 + quad * 4 + r][ql] = o01[r];
    sm.osh[w][1][quad * 4 + r][ql] = o10[r];
    sm.osh[w][1][16 + quad * 4 + r][ql] = o11[r];
  }
  if (quad == 0) {
    lsh[w][0][ql] = lrun0;
    lsh[w][1][ql] = lrun1;
  }
  __syncthreads();

  if (w < 2) {
    int qt = w;
    float l = 0.f;
    f32x4 a0 = {0.f, 0.f, 0.f, 0.f}, a1 = {0.f, 0.f, 0.f, 0.f};
#pragma unroll
    for (int i = 0; i < NW; ++i) {
      l += lsh[i][qt][ql];
#pragma unroll
      for (int r = 0; r < 4; ++r) {
        a0[r] += sm.osh[i][qt][quad * 4 + r][ql];
        a1[r] += sm.osh[i][qt][16 + quad * 4 + r][ql];
      }
    }
    float inv = 1.0f / l;
    s16x4 w0, w1;
#pragma unroll
    for (int r = 0; r < 4; ++r) {
      w0[r] = (short)f2b(a0[r] * inv);
      w1[r] = (short)f2b(a1[r] * inv);
    }
    *(s16x4*)(&Olds[qt][ql][quad * 4]) = w0;
    *(s16x4*)(&Olds[qt][ql][16 + quad * 4]) = w1;
    __builtin_amdgcn_s_waitcnt(0xC07F);
    __builtin_amdgcn_wave_barrier();
    bf16x8 of = *(const bf16x8*)(&Olds[qt][ql][quad * 8]);

    const float* wzr0 = Wz + (size_t)ql * (2 * DM) + ph * DM + quad * 8;
    const float* wzr1 = Wz + (size_t)(ql + 16) * (2 * DM) + ph * DM + quad * 8;
    bf16x8 a0f, a1f;
#pragma unroll
    for (int j = 0; j < 8; ++j) {
      a0f[j] = (short)f2b(wzr0[j]);
      a1f[j] = (short)f2b(wzr1[j]);
    }
    f32x4 z0 = {0.f, 0.f, 0.f, 0.f}, z1 = {0.f, 0.f, 0.f, 0.f};
    if (ph == 0) {
#pragma unroll
      for (int r = 0; r < 4; ++r) {
        z0[r] = bz[quad * 4 + r];
        z1[r] = bz[16 + quad * 4 + r];
      }
    }
    z0 = __builtin_amdgcn_mfma_f32_16x16x32_bf16(a0f, of, z0, 0, 0, 0);
    z1 = __builtin_amdgcn_mfma_f32_16x16x32_bf16(a1f, of, z1, 0, 0, 0);
    int qc = q0 + qt * 16 + ql;
#pragma unroll
    for (int r = 0; r < 4; ++r) {
      Zp[(size_t)(quad * 4 + r) * S + qc] = f2b(z0[r]);
      Zp[(size_t)(16 + quad * 4 + r) * S + qc] = f2b(z1[r]);
    }
  }
}

// ---------------- K3: conv v5 — 8-wave blocks, 32 s/wave, k-split x2 -----
// Block = one image row y (256 blocks). Wave w: kk = w>>2 (k-half),
// r2 = w&3: g = r2&1 (co half), x0 = (r2>>1)*32 (32 s positions, 2 B-frags
// per weight frag -> weight L2 traffic halves vs r13). k-split partials
// (fp32) merged via LDS. Halo filled once per row (was twice).
__global__ __launch_bounds__(512) void conv_mfma_kernel(
    const float* __restrict__ ws, const float* __restrict__ h,
    const float* __restrict__ m, const float* __restrict__ bo,
    float* __restrict__ out) {
  __shared__ unsigned short xt[3][66][96];        // 38016 B (16B-aligned rows)
  __shared__ __align__(16) float mbuf[4][6][64][4];  // 24576 B merge buffer
  int bid = blockIdx.x;
  int n = bid >> 6;
  int y = bid & 63;
  int tid = threadIdx.x;
  int w = tid >> 6;
  int lane = tid & 63;
  int ql = lane & 15, quad = lane >> 4;
  int kk = w >> 2;
  int r2 = w & 3;
  int g = r2 & 1;
  int x0 = (r2 >> 1) * 32;

  const unsigned short* Zh = (const unsigned short*)(ws + OFF_ZH) + (size_t)n * DM * S;
  const unsigned short* Zm = (const unsigned short*)(ws + OFF_ZM) + (size_t)n * DM * S;
  const float* hb = h + (size_t)n * CIN * S;
  const unsigned short* Wf = (const unsigned short*)(ws + OFF_WF);

  // halo: 3 rows x 64 x x 12 blocks-of-8ci = 2304 b128 writes over 512 thr
#pragma unroll
  for (int k = 0; k < 5; ++k) {
    int idx = tid + k * 512;
    if (idx < 2304) {
      int xm1 = idx & 63;
      int t2 = idx >> 6;       // 0..35
      int cb = t2 % 12;
      int r3 = t2 / 12;
      int yy = y + r3 - 1;
      u32x4 val = {0u, 0u, 0u, 0u};
      if (yy >= 0 && yy < 64) {
        int s = yy * 64 + xm1;
        int ci0 = cb * 8;
        float a[8];
        if (ci0 < 32) {
#pragma unroll
          for (int j = 0; j < 8; ++j)
            a[j] = b2f(Zh[(size_t)(ci0 + j) * S + s]) + b2f(Zm[(size_t)(ci0 + j) * S + s]);
        } else {
#pragma unroll
          for (int j = 0; j < 8; ++j)
            a[j] = hb[(size_t)(ci0 - 32 + j) * S + s];
        }
#pragma unroll
        for (int t = 0; t < 4; ++t)
          val[t] = (unsigned)f2b(a[2 * t]) | ((unsigned)f2b(a[2 * t + 1]) << 16);
      }
      *(u32x4*)(&xt[r3][xm1 + 1][cb * 8]) = val;
    }
  }
  // x guard columns (x=0 and x=65): 72 b128 writes
  if (tid < 72) {
    int r3 = tid / 24;
    int rm = tid % 24;
    int side = rm / 12;
    int cb = rm % 12;
    *(u32x4*)(&xt[r3][side * 65][cb * 8]) = (u32x4){0u, 0u, 0u, 0u};
  }
  __syncthreads();

  f32x4 acc0[6], acc1[6];
#pragma unroll
  for (int t = 0; t < 6; ++t) {
    acc0[t] = (f32x4){0.f, 0.f, 0.f, 0.f};
    acc1[t] = (f32x4){0.f, 0.f, 0.f, 0.f};
  }

  const unsigned short* wfb[6];
#pragma unroll
  for (int j = 0; j < 6; ++j) {
    int t12 = (j >> 1) * 4 + g * 2 + (j & 1);
    wfb[j] = Wf + (size_t)t12 * 27 * 512 + lane * 8;
  }

  int kb_lo = kk * 14;
  int kb_hi = kk ? 27 : 14;
  for (int kb = kb_lo; kb < kb_hi; ++kb) {
    int dy = kb / 9;
    int rem = kb % 9;
    int dx = rem / 3;
    int cc = rem % 3;
    bf16x8 b0 = *(const bf16x8*)(&xt[dy][x0 + ql + dx][cc * 32 + quad * 8]);
    bf16x8 b1 = *(const bf16x8*)(&xt[dy][x0 + 16 + ql + dx][cc * 32 + quad * 8]);
#pragma unroll
    for (int j = 0; j < 6; ++j) {
      bf16x8 wf = *(const bf16x8*)(wfb[j] + (size_t)kb * 512);
      acc0[j] = __builtin_amdgcn_mfma_f32_16x16x32_bf16(wf, b0, acc0[j], 0, 0, 0);
      acc1[j] = __builtin_amdgcn_mfma_f32_16x16x32_bf16(wf, b1, acc1[j], 0, 0, 0);
    }
  }

  // ---- k-split merge: kk=1 partials -> LDS -> kk=0 adds ----
  if (kk == 1) {
#pragma unroll
    for (int j = 0; j < 6; ++j) *(f32x4*)(&mbuf[r2][j][lane][0]) = acc0[j];
  }
  __syncthreads();
  if (kk == 0) {
#pragma unroll
    for (int j = 0; j < 6; ++j) acc0[j] += *(const f32x4*)(&mbuf[r2][j][lane][0]);
  }
  __syncthreads();
  if (kk == 1) {
#pragma unroll
    for (int j = 0; j < 6; ++j) *(f32x4*)(&mbuf[r2][j][lane][0]) = acc1[j];
  }
  __syncthreads();
  if (kk == 0) {
#pragma unroll
    for (int j = 0; j < 6; ++j) acc1[j] += *(const f32x4*)(&mbuf[r2][j][lane][0]);

    // ---- gating epilogue for both 16-s fragments ----
#pragma unroll
    for (int sfr = 0; sfr < 2; ++sfr) {
      f32x4* ac = sfr ? acc1 : acc0;
      int s = y * 64 + x0 + sfr * 16 + ql;
#pragma unroll
      for (int jj = 0; jj < 2; ++jj) {
#pragma unroll
        for (int r = 0; r < 4; ++r) {
          int c = g * 32 + jj * 16 + quad * 4 + r;
          float iv = ac[jj][r] + bo[c];
          float gv = ac[2 + jj][r] + bo[64 + c];
          float ov = ac[4 + jj][r] + bo[128 + c];
          float ig = 1.f / (1.f + __expf(-iv));
          float gg = tanhf(gv);
          float og = 1.f / (1.f + __expf(-ov));
          size_t oidx = (((size_t)n * 64 + c) << 12) + s;
          float mold = m[oidx];
          float mn = ig * gg + (1.f - ig) * mold;
          out[oidx] = og * mn;
          out[(size_t)NB * CIN * S + oidx] = mn;
        }
      }
    }
  }
}

extern "C" void kernel_launch(void* const* d_in, const int* in_sizes, int n_in,
                              void* d_out, int out_size, void* d_ws, size_t ws_size,
                              hipStream_t stream) {
  const float* h = (const float*)d_in[0];
  const float* m = (const float*)d_in[1];
  const float* Wh = (const float*)d_in[2];
  const float* bh = (const float*)d_in[3];
  const float* Wm = (const float*)d_in[4];
  const float* bm = (const float*)d_in[5];
  const float* Wz = (const float*)d_in[6];
  const float* bz = (const float*)d_in[7];
  const float* Wo = (const float*)d_in[8];
  const float* bo = (const float*)d_in[9];
  float* out = (float*)d_out;
  float* ws = (float*)d_ws;

  prep_kernel<<<836, 256, 0, stream>>>(h, m, Wh, bh, Wm, bm, Wo, ws);
  attn_kernel<<<2 * NB * (S / 32), 256, 0, stream>>>(ws, Wz, bz);
  conv_mfma_kernel<<<NB * 64, 512, 0, stream>>>(ws, h, m, bo, out);
}